// Round 1
// baseline (721.012 us; speedup 1.0000x reference)
//
#include <hip/hip_runtime.h>
#include <math.h>

// HOG multi-scale feature extractor for 28x28 images.
// One 256-thread block per image. All intermediates in LDS; coalesced
// float4 global read (image) and write (8296-dim feature row).

constexpr int NPIX = 784;          // 28*28
constexpr int FEAT = 8296;         // 784 + 1152 + 2304 + 4056
// histogram sizes: cell=4 -> 7*7*8=392 ; cell=3 -> 9*9*9=729 ; cell=2 -> 14*14*6=1176
constexpr int O4 = 0;
constexpr int O3 = 392;
constexpr int O2 = 392 + 729;      // 1121
constexpr int HIST_TOT = 392 + 729 + 1176; // 2297

__device__ __forceinline__ float ldimg(const float* img, int y, int x) {
    return (y >= 0 && y < 28 && x >= 0 && x < 28) ? img[y * 28 + x] : 0.0f;
}

__device__ __forceinline__ void accum_hist(float* h, int cell, int bins,
                                           float binw, float inv_binw,
                                           float ang, float mag) {
    int b0 = (int)floorf(ang * inv_binw);
    b0 = min(max(b0, 0), bins - 1);
    float frac = (ang - (float)b0 * binw) * inv_binw;
    int b1 = b0 + 1;
    if (b1 == bins) b1 = 0;
    atomicAdd(&h[cell * bins + b0], mag * (1.0f - frac));
    atomicAdd(&h[cell * bins + b1], mag * frac);
}

__global__ __launch_bounds__(256)
void hog_kernel(const float* __restrict__ x,
                const float* __restrict__ fmean,
                const float* __restrict__ fstd,
                float* __restrict__ out, int B) {
    __shared__ __align__(16) float img[NPIX];
    __shared__ float hist[HIST_TOT];
    __shared__ __align__(16) float feat[FEAT];

    const int b = blockIdx.x;
    const int tid = threadIdx.x;
    const float* xb = x + (size_t)b * NPIX;

    // ---- load image (784 floats = 196 float4, coalesced) ----
    for (int i = tid; i < NPIX / 4; i += 256)
        reinterpret_cast<float4*>(img)[i] =
            reinterpret_cast<const float4*>(xb)[i];
    // ---- zero histograms ----
    for (int i = tid; i < HIST_TOT; i += 256) hist[i] = 0.0f;
    __syncthreads();

    // ---- Sobel + magnitude/angle + soft binning into 3 histograms ----
    for (int p = tid; p < NPIX; p += 256) {
        int y = p / 28, xx = p - (p / 28) * 28;
        float a00 = ldimg(img, y - 1, xx - 1);
        float a01 = ldimg(img, y - 1, xx);
        float a02 = ldimg(img, y - 1, xx + 1);
        float a10 = ldimg(img, y,     xx - 1);
        float a12 = ldimg(img, y,     xx + 1);
        float a20 = ldimg(img, y + 1, xx - 1);
        float a21 = ldimg(img, y + 1, xx);
        float a22 = ldimg(img, y + 1, xx + 1);
        float gxv = (a00 + 2.0f * a10 + a20 - a02 - 2.0f * a12 - a22) * 0.25f;
        float gyv = (a00 + 2.0f * a01 + a02 - a20 - 2.0f * a21 - a22) * 0.25f;
        float mag = sqrtf(gxv * gxv + gyv * gyv + 1e-6f);
        float ang = atan2f(gyv, gxv) * 57.29577951308232f; // 180/pi
        ang = fmodf(ang + 180.0f, 180.0f);

        { // cell=4, bins=8, Hc=Wc=7
            int cy = y >> 2, cx = xx >> 2;
            accum_hist(hist + O4, cy * 7 + cx, 8, 22.5f, 1.0f / 22.5f, ang, mag);
        }
        { // cell=3, bins=9, Hc=Wc=9 (last cell absorbs row/col 27 via clip)
            int cy = y / 3; if (cy > 8) cy = 8;
            int cx = xx / 3; if (cx > 8) cx = 8;
            accum_hist(hist + O3, cy * 9 + cx, 9, 20.0f, 0.05f, ang, mag);
        }
        { // cell=2, bins=6, Hc=Wc=14
            int cy = y >> 1, cx = xx >> 1;
            accum_hist(hist + O2, cy * 14 + cx, 6, 30.0f, 1.0f / 30.0f, ang, mag);
        }
    }
    __syncthreads();

    // ---- flat image part of the feature vector ----
    for (int i = tid; i < NPIX; i += 256) feat[i] = img[i];

    // ---- block normalization (L2-hys): 36 + 64 + 169 = 269 tasks ----
    for (int t = tid; t < 269; t += 256) {
        int bins, Wc, hoff, foff, by, bx;
        if (t < 36) {            // h4: 6x6 blocks, 32 values
            bins = 8; Wc = 7; hoff = O4;
            by = t / 6; bx = t - by * 6;
            foff = 784 + t * 32;
        } else if (t < 100) {    // h3: 8x8 blocks, 36 values
            int k = t - 36;
            bins = 9; Wc = 9; hoff = O3;
            by = k >> 3; bx = k & 7;
            foff = 1936 + k * 36;
        } else {                 // h2: 13x13 blocks, 24 values
            int k = t - 100;
            bins = 6; Wc = 14; hoff = O2;
            by = k / 13; bx = k - by * 13;
            foff = 4240 + k * 24;
        }
        int c00 = (by * Wc + bx) * bins;
        int cb[4] = {c00, c00 + bins, c00 + Wc * bins, c00 + (Wc + 1) * bins};

        float s = 0.0f;
        #pragma unroll
        for (int q = 0; q < 4; ++q)
            for (int j = 0; j < bins; ++j) {
                float v = hist[hoff + cb[q] + j];
                s += v * v;
            }
        float ninv = 1.0f / sqrtf(s + 1e-6f);

        float s2 = 0.0f;
        #pragma unroll
        for (int q = 0; q < 4; ++q)
            for (int j = 0; j < bins; ++j) {
                float c = fminf(hist[hoff + cb[q] + j] * ninv, 0.2f);
                s2 += c * c;
            }
        float n2inv = 1.0f / sqrtf(s2 + 1e-6f);

        #pragma unroll
        for (int q = 0; q < 4; ++q)
            for (int j = 0; j < bins; ++j) {
                float c = fminf(hist[hoff + cb[q] + j] * ninv, 0.2f);
                feat[foff + q * bins + j] = c * n2inv;
            }
    }
    __syncthreads();

    // ---- epilogue: (feat - mean) / std, coalesced float4 writes ----
    float4* outp = reinterpret_cast<float4*>(out + (size_t)b * FEAT);
    const float4* m4 = reinterpret_cast<const float4*>(fmean);
    const float4* s4 = reinterpret_cast<const float4*>(fstd);
    const float4* f4 = reinterpret_cast<const float4*>(feat);
    for (int i = tid; i < FEAT / 4; i += 256) {
        float4 v = f4[i];
        float4 m = m4[i];
        float4 sd = s4[i];
        float4 r;
        r.x = (v.x - m.x) / sd.x;
        r.y = (v.y - m.y) / sd.y;
        r.z = (v.z - m.z) / sd.z;
        r.w = (v.w - m.w) / sd.w;
        outp[i] = r;
    }
}

extern "C" void kernel_launch(void* const* d_in, const int* in_sizes, int n_in,
                              void* d_out, int out_size, void* d_ws, size_t ws_size,
                              hipStream_t stream) {
    const float* x     = (const float*)d_in[0];
    const float* fmean = (const float*)d_in[1];
    const float* fstd  = (const float*)d_in[2];
    float* out = (float*)d_out;
    int B = in_sizes[0] / NPIX;
    hipLaunchKernelGGL(hog_kernel, dim3(B), dim3(256), 0, stream,
                       x, fmean, fstd, out, B);
}

// Round 2
// 529.444 us; speedup vs baseline: 1.3618x; 1.3618x over previous
//
#include <hip/hip_runtime.h>
#include <math.h>

// HOG multi-scale feature extractor for 28x28 images.
// One 256-thread block per image. Key changes vs v1:
//  - no LDS feat[] buffer: epilogue inverts the output index -> (task,q,bin)
//    mapping and reads hist + per-task norm factors directly (LDS 45.5->15.8KB,
//    occupancy 3->8 blocks/CU)
//  - hist cell stride padded to bins+1 (9/10/7) to break 16-way bank conflicts

constexpr int NPIX = 784;          // 28*28
constexpr int FEAT = 8296;         // 784 + 1152 + 2304 + 4056
// padded histogram layout: cell stride = bins+1
constexpr int PB4 = 9;             // cell=4: 7*7 cells, 8 bins
constexpr int PB3 = 10;            // cell=3: 9*9 cells, 9 bins
constexpr int PB2 = 7;             // cell=2: 14*14 cells, 6 bins
constexpr int O4P = 0;             // 49*9  = 441
constexpr int O3P = 441;           // 81*10 = 810
constexpr int O2P = 441 + 810;     // 1251 ; 196*7 = 1372
constexpr int HIST_TOT = O2P + 1372; // 2623 floats = 10.5 KB
constexpr int NTASK = 269;         // 36 + 64 + 169 block-norm tasks

__device__ __forceinline__ float ldimg(const float* img, int y, int x) {
    return (y >= 0 && y < 28 && x >= 0 && x < 28) ? img[y * 28 + x] : 0.0f;
}

__device__ __forceinline__ void accum_hist(float* h, int base, int bins,
                                           float binw, float inv_binw,
                                           float ang, float mag) {
    int b0 = (int)floorf(ang * inv_binw);
    b0 = min(max(b0, 0), bins - 1);
    float frac = (ang - (float)b0 * binw) * inv_binw;
    int b1 = b0 + 1;
    if (b1 == bins) b1 = 0;
    atomicAdd(&h[base + b0], mag * (1.0f - frac));
    atomicAdd(&h[base + b1], mag * frac);
}

__global__ __launch_bounds__(256)
void hog_kernel(const float* __restrict__ x,
                const float* __restrict__ fmean,
                const float* __restrict__ fstd,
                float* __restrict__ out, int B) {
    __shared__ __align__(16) float img[NPIX];
    __shared__ float hist[HIST_TOT];
    __shared__ float2 nrm[NTASK];

    const int b = blockIdx.x;
    const int tid = threadIdx.x;
    const float* xb = x + (size_t)b * NPIX;

    // ---- load image (coalesced float4) + zero hist ----
    for (int i = tid; i < NPIX / 4; i += 256)
        reinterpret_cast<float4*>(img)[i] =
            reinterpret_cast<const float4*>(xb)[i];
    for (int i = tid; i < HIST_TOT; i += 256) hist[i] = 0.0f;
    __syncthreads();

    // ---- Sobel + magnitude/angle + soft binning into 3 padded histograms ----
    for (int p = tid; p < NPIX; p += 256) {
        int y = p / 28, xx = p - (p / 28) * 28;
        float a00 = ldimg(img, y - 1, xx - 1);
        float a01 = ldimg(img, y - 1, xx);
        float a02 = ldimg(img, y - 1, xx + 1);
        float a10 = ldimg(img, y,     xx - 1);
        float a12 = ldimg(img, y,     xx + 1);
        float a20 = ldimg(img, y + 1, xx - 1);
        float a21 = ldimg(img, y + 1, xx);
        float a22 = ldimg(img, y + 1, xx + 1);
        float gxv = (a00 + 2.0f * a10 + a20 - a02 - 2.0f * a12 - a22) * 0.25f;
        float gyv = (a00 + 2.0f * a01 + a02 - a20 - 2.0f * a21 - a22) * 0.25f;
        float mag = sqrtf(gxv * gxv + gyv * gyv + 1e-6f);
        float ang = atan2f(gyv, gxv) * 57.29577951308232f; // 180/pi
        ang = fmodf(ang + 180.0f, 180.0f);

        { // cell=4, bins=8, Hc=Wc=7
            int base = ((y >> 2) * 7 + (xx >> 2)) * PB4;
            accum_hist(hist, O4P + base, 8, 22.5f, 1.0f / 22.5f, ang, mag);
        }
        { // cell=3, bins=9, Hc=Wc=9 (row/col 27 clipped into last cell)
            int cy = y / 3; if (cy > 8) cy = 8;
            int cx = xx / 3; if (cx > 8) cx = 8;
            accum_hist(hist, O3P + (cy * 9 + cx) * PB3, 9, 20.0f, 0.05f, ang, mag);
        }
        { // cell=2, bins=6, Hc=Wc=14
            int base = ((y >> 1) * 14 + (xx >> 1)) * PB2;
            accum_hist(hist, O2P + base, 6, 30.0f, 1.0f / 30.0f, ang, mag);
        }
    }
    __syncthreads();

    // ---- norm factors only (2 floats per task; no feat staging) ----
    for (int t = tid; t < NTASK; t += 256) {
        int bins, Wc, pb, hoff, by, bx;
        if (t < 36) {            // h4: 6x6 blocks
            bins = 8; pb = PB4; Wc = 7; hoff = O4P;
            by = t / 6; bx = t - by * 6;
        } else if (t < 100) {    // h3: 8x8 blocks
            int k = t - 36;
            bins = 9; pb = PB3; Wc = 9; hoff = O3P;
            by = k >> 3; bx = k & 7;
        } else {                 // h2: 13x13 blocks
            int k = t - 100;
            bins = 6; pb = PB2; Wc = 14; hoff = O2P;
            by = k / 13; bx = k - by * 13;
        }
        int c00 = hoff + (by * Wc + bx) * pb;
        int cb[4] = {c00, c00 + pb, c00 + Wc * pb, c00 + (Wc + 1) * pb};

        float s = 0.0f;
        #pragma unroll
        for (int q = 0; q < 4; ++q)
            for (int j = 0; j < bins; ++j) {
                float v = hist[cb[q] + j];
                s += v * v;
            }
        float ninv = 1.0f / sqrtf(s + 1e-6f);

        float s2 = 0.0f;
        #pragma unroll
        for (int q = 0; q < 4; ++q)
            for (int j = 0; j < bins; ++j) {
                float c = fminf(hist[cb[q] + j] * ninv, 0.2f);
                s2 += c * c;
            }
        nrm[t] = make_float2(ninv, 1.0f / sqrtf(s2 + 1e-6f));
    }
    __syncthreads();

    // ---- epilogue: invert index mapping, (v-mean)/std, coalesced float4 ----
    float4* outp = reinterpret_cast<float4*>(out + (size_t)b * FEAT);
    const float4* m4 = reinterpret_cast<const float4*>(fmean);
    const float4* s4 = reinterpret_cast<const float4*>(fstd);
    for (int i4 = tid; i4 < FEAT / 4; i4 += 256) {
        float vv[4];
        #pragma unroll
        for (int e = 0; e < 4; ++e) {
            int i = i4 * 4 + e;
            float val;
            if (i < 784) {
                val = img[i];
            } else if (i < 1936) {          // h4: 36 tasks x 4q x 8 bins
                int k = i - 784;
                int t = k >> 5, r = k & 31;
                int q = r >> 3, j = r & 7;
                int by = t / 6, bx = t - by * 6;
                int h = O4P + ((by + (q >> 1)) * 7 + bx + (q & 1)) * PB4 + j;
                float2 n = nrm[t];
                val = fminf(hist[h] * n.x, 0.2f) * n.y;
            } else if (i < 4240) {          // h3: 64 tasks x 4q x 9 bins
                int k = i - 1936;
                int t = k / 36, r = k - t * 36;
                int q = r / 9,  j = r - q * 9;
                int by = t >> 3, bx = t & 7;
                int h = O3P + ((by + (q >> 1)) * 9 + bx + (q & 1)) * PB3 + j;
                float2 n = nrm[36 + t];
                val = fminf(hist[h] * n.x, 0.2f) * n.y;
            } else {                        // h2: 169 tasks x 4q x 6 bins
                int k = i - 4240;
                int t = k / 24, r = k - t * 24;
                int q = r / 6,  j = r - q * 6;
                int by = t / 13, bx = t - by * 13;
                int h = O2P + ((by + (q >> 1)) * 14 + bx + (q & 1)) * PB2 + j;
                float2 n = nrm[100 + t];
                val = fminf(hist[h] * n.x, 0.2f) * n.y;
            }
            vv[e] = val;
        }
        float4 m = m4[i4];
        float4 sd = s4[i4];
        float4 r;
        r.x = (vv[0] - m.x) / sd.x;
        r.y = (vv[1] - m.y) / sd.y;
        r.z = (vv[2] - m.z) / sd.z;
        r.w = (vv[3] - m.w) / sd.w;
        outp[i4] = r;
    }
}

extern "C" void kernel_launch(void* const* d_in, const int* in_sizes, int n_in,
                              void* d_out, int out_size, void* d_ws, size_t ws_size,
                              hipStream_t stream) {
    const float* x     = (const float*)d_in[0];
    const float* fmean = (const float*)d_in[1];
    const float* fstd  = (const float*)d_in[2];
    float* out = (float*)d_out;
    int B = in_sizes[0] / NPIX;
    hipLaunchKernelGGL(hog_kernel, dim3(B), dim3(256), 0, stream,
                       x, fmean, fstd, out, B);
}

// Round 3
// 490.786 us; speedup vs baseline: 1.4691x; 1.0788x over previous
//
#include <hip/hip_runtime.h>
#include <math.h>

// HOG multi-scale feature extractor for 28x28 images. v3:
//  - atan2f/fmodf replaced by branchless poly atan (orientation in [0,180))
//  - epilogue index inversion precomputed once into d_ws by a setup kernel:
//    map[i] = (task<<12)|hist_idx ; msr[i] = (mean[i], 1/std[i])
//  - LDS 15.8KB/block (img + padded hist + norm factors), 8 blocks/CU

constexpr int NPIX = 784;
constexpr int FEAT = 8296;            // 784 + 1152 + 2304 + 4056
constexpr int PB4 = 9, PB3 = 10, PB2 = 7;   // padded cell strides (bins+1)
constexpr int O4P = 0, O3P = 441, O2P = 1251;
constexpr int HIST_TOT = 2623;        // 441 + 810 + 1372 floats
constexpr int NTASK = 269;            // 36 + 64 + 169 block-norm tasks
constexpr int NHOG = FEAT - NPIX;     // 7512 table entries

// ---- output index i in [784,8296) -> packed (task<<12)|hist_idx ----
__device__ __forceinline__ int feat_map(int i) {
    int task, h;
    if (i < 1936) {                    // h4: 36 tasks x 4q x 8 bins
        int k = i - 784;
        int t = k >> 5, r = k & 31;
        int q = r >> 3, j = r & 7;
        int by = t / 6, bx = t - by * 6;
        h = O4P + ((by + (q >> 1)) * 7 + bx + (q & 1)) * PB4 + j;
        task = t;
    } else if (i < 4240) {             // h3: 64 tasks x 4q x 9 bins
        int k = i - 1936;
        int t = k / 36, r = k - t * 36;
        int q = r / 9,  j = r - q * 9;
        int by = t >> 3, bx = t & 7;
        h = O3P + ((by + (q >> 1)) * 9 + bx + (q & 1)) * PB3 + j;
        task = 36 + t;
    } else {                           // h2: 169 tasks x 4q x 6 bins
        int k = i - 4240;
        int t = k / 24, r = k - t * 24;
        int q = r / 6,  j = r - q * 6;
        int by = t / 13, bx = t - by * 13;
        h = O2P + ((by + (q >> 1)) * 14 + bx + (q & 1)) * PB2 + j;
        task = 100 + t;
    }
    return (task << 12) | h;
}

__global__ __launch_bounds__(256)
void setup_kernel(const float* __restrict__ fmean,
                  const float* __restrict__ fstd,
                  float2* __restrict__ msr, int* __restrict__ map) {
    int i = blockIdx.x * 256 + threadIdx.x;
    if (i < FEAT) {
        msr[i] = make_float2(fmean[i], 1.0f / fstd[i]);
        if (i >= NPIX) map[i - NPIX] = feat_map(i);
    }
}

// branchless orientation in degrees, == (atan2(gy,gx)*180/pi + 180) mod 180
// up to continuity at the 0/180 wrap (exact w.r.t. the soft-binning).
__device__ __forceinline__ float orient_deg(float gy, float gx) {
    float ax = fabsf(gx), ay = fabsf(gy);
    float mn = fminf(ax, ay), mx = fmaxf(ax, ay);
    float r = __fdividef(mn, mx + 1e-37f);          // [0,1]
    float a = r * r;                                 // A&S 4.4.49, |err|<=1e-5
    float th = ((((0.0208351f * a - 0.0851330f) * a + 0.1801410f) * a
                 - 0.3302995f) * a + 0.9998660f) * r;
    th *= 57.29577951308232f;                        // rad -> deg, [0,45]
    if (ay > ax) th = 90.0f - th;                    // [0,90]
    bool neg = ((__float_as_uint(gx) ^ __float_as_uint(gy)) >> 31) != 0;
    float o = neg ? 180.0f - th : th;
    return (o >= 180.0f) ? 0.0f : o;                 // continuous wrap
}

__device__ __forceinline__ float ldimg(const float* img, int y, int x) {
    return (y >= 0 && y < 28 && x >= 0 && x < 28) ? img[y * 28 + x] : 0.0f;
}

__device__ __forceinline__ void accum_hist(float* h, int base, int bins,
                                           float binw, float inv_binw,
                                           float ang, float mag) {
    int b0 = (int)(ang * inv_binw);                  // ang >= 0
    b0 = min(max(b0, 0), bins - 1);
    float frac = (ang - (float)b0 * binw) * inv_binw;
    int b1 = b0 + 1;
    if (b1 == bins) b1 = 0;
    atomicAdd(&h[base + b0], mag * (1.0f - frac));
    atomicAdd(&h[base + b1], mag * frac);
}

template <bool USE_TABLE>
__global__ __launch_bounds__(256)
void hog_kernel(const float* __restrict__ x,
                const float* __restrict__ fmean,
                const float* __restrict__ fstd,
                const float2* __restrict__ msr,
                const int* __restrict__ map,
                float* __restrict__ out) {
    __shared__ __align__(16) float img[NPIX];
    __shared__ float hist[HIST_TOT];
    __shared__ float2 nrm[NTASK];

    const int b = blockIdx.x;
    const int tid = threadIdx.x;
    const float* xb = x + (size_t)b * NPIX;

    // ---- load image (coalesced float4) + zero hist ----
    for (int i = tid; i < NPIX / 4; i += 256)
        reinterpret_cast<float4*>(img)[i] =
            reinterpret_cast<const float4*>(xb)[i];
    for (int i = tid; i < HIST_TOT; i += 256) hist[i] = 0.0f;
    __syncthreads();

    // ---- Sobel + orientation + soft binning (LDS float atomics) ----
    for (int p = tid; p < NPIX; p += 256) {
        int y = p / 28, xx = p - (p / 28) * 28;
        float a00 = ldimg(img, y - 1, xx - 1);
        float a01 = ldimg(img, y - 1, xx);
        float a02 = ldimg(img, y - 1, xx + 1);
        float a10 = ldimg(img, y,     xx - 1);
        float a12 = ldimg(img, y,     xx + 1);
        float a20 = ldimg(img, y + 1, xx - 1);
        float a21 = ldimg(img, y + 1, xx);
        float a22 = ldimg(img, y + 1, xx + 1);
        float gxv = (a00 + 2.0f * a10 + a20 - a02 - 2.0f * a12 - a22) * 0.25f;
        float gyv = (a00 + 2.0f * a01 + a02 - a20 - 2.0f * a21 - a22) * 0.25f;
        float mag = sqrtf(gxv * gxv + gyv * gyv + 1e-6f);
        float ang = orient_deg(gyv, gxv);

        {   // cell=4, bins=8
            int base = O4P + ((y >> 2) * 7 + (xx >> 2)) * PB4;
            accum_hist(hist, base, 8, 22.5f, 1.0f / 22.5f, ang, mag);
        }
        {   // cell=3, bins=9 (row/col 27 clipped into last cell)
            int cy = y / 3; if (cy > 8) cy = 8;
            int cx = xx / 3; if (cx > 8) cx = 8;
            accum_hist(hist, O3P + (cy * 9 + cx) * PB3, 9, 20.0f, 0.05f, ang, mag);
        }
        {   // cell=2, bins=6
            int base = O2P + ((y >> 1) * 14 + (xx >> 1)) * PB2;
            accum_hist(hist, base, 6, 30.0f, 1.0f / 30.0f, ang, mag);
        }
    }
    __syncthreads();

    // ---- per-task L2-hys norm factors ----
    for (int t = tid; t < NTASK; t += 256) {
        int bins, Wc, pb, hoff, by, bx;
        if (t < 36)       { bins = 8; pb = PB4; Wc = 7;  hoff = O4P;
                            by = t / 6; bx = t - by * 6; }
        else if (t < 100) { int k = t - 36; bins = 9; pb = PB3; Wc = 9; hoff = O3P;
                            by = k >> 3; bx = k & 7; }
        else              { int k = t - 100; bins = 6; pb = PB2; Wc = 14; hoff = O2P;
                            by = k / 13; bx = k - by * 13; }
        int c00 = hoff + (by * Wc + bx) * pb;
        int cb[4] = {c00, c00 + pb, c00 + Wc * pb, c00 + (Wc + 1) * pb};

        float s = 0.0f;
        #pragma unroll
        for (int q = 0; q < 4; ++q)
            for (int j = 0; j < bins; ++j) {
                float v = hist[cb[q] + j];
                s += v * v;
            }
        float ninv = 1.0f / sqrtf(s + 1e-6f);

        float s2 = 0.0f;
        #pragma unroll
        for (int q = 0; q < 4; ++q)
            for (int j = 0; j < bins; ++j) {
                float c = fminf(hist[cb[q] + j] * ninv, 0.2f);
                s2 += c * c;
            }
        nrm[t] = make_float2(ninv, 1.0f / sqrtf(s2 + 1e-6f));
    }
    __syncthreads();

    // ---- epilogue: coalesced float4 writes ----
    float4* outp = reinterpret_cast<float4*>(out + (size_t)b * FEAT);

    // flat image part: 196 float4
    for (int i4 = tid; i4 < NPIX / 4; i4 += 256) {
        float4 v = reinterpret_cast<const float4*>(img)[i4];
        float4 r;
        if (USE_TABLE) {
            const float4* msr4 = reinterpret_cast<const float4*>(msr);
            float4 p0 = msr4[i4 * 2], p1 = msr4[i4 * 2 + 1];
            r.x = (v.x - p0.x) * p0.y;  r.y = (v.y - p0.z) * p0.w;
            r.z = (v.z - p1.x) * p1.y;  r.w = (v.w - p1.z) * p1.w;
        } else {
            int i = i4 * 4;
            r.x = (v.x - fmean[i])     / fstd[i];
            r.y = (v.y - fmean[i + 1]) / fstd[i + 1];
            r.z = (v.z - fmean[i + 2]) / fstd[i + 2];
            r.w = (v.w - fmean[i + 3]) / fstd[i + 3];
        }
        outp[i4] = r;
    }

    // HOG part: 1878 float4 via precomputed map
    for (int t4 = tid; t4 < NHOG / 4; t4 += 256) {
        int i4 = NPIX / 4 + t4;
        int mp[4];
        if (USE_TABLE) {
            int4 m4 = reinterpret_cast<const int4*>(map)[t4];
            mp[0] = m4.x; mp[1] = m4.y; mp[2] = m4.z; mp[3] = m4.w;
        } else {
            #pragma unroll
            for (int e = 0; e < 4; ++e) mp[e] = feat_map(i4 * 4 + e);
        }
        float vv[4];
        #pragma unroll
        for (int e = 0; e < 4; ++e) {
            int task = mp[e] >> 12, h = mp[e] & 4095;
            float2 n = nrm[task];
            vv[e] = fminf(hist[h] * n.x, 0.2f) * n.y;
        }
        float4 r;
        if (USE_TABLE) {
            const float4* msr4 = reinterpret_cast<const float4*>(msr);
            float4 p0 = msr4[i4 * 2], p1 = msr4[i4 * 2 + 1];
            r.x = (vv[0] - p0.x) * p0.y;  r.y = (vv[1] - p0.z) * p0.w;
            r.z = (vv[2] - p1.x) * p1.y;  r.w = (vv[3] - p1.z) * p1.w;
        } else {
            int i = i4 * 4;
            r.x = (vv[0] - fmean[i])     / fstd[i];
            r.y = (vv[1] - fmean[i + 1]) / fstd[i + 1];
            r.z = (vv[2] - fmean[i + 2]) / fstd[i + 2];
            r.w = (vv[3] - fmean[i + 3]) / fstd[i + 3];
        }
        outp[i4] = r;
    }
}

extern "C" void kernel_launch(void* const* d_in, const int* in_sizes, int n_in,
                              void* d_out, int out_size, void* d_ws, size_t ws_size,
                              hipStream_t stream) {
    const float* x     = (const float*)d_in[0];
    const float* fmean = (const float*)d_in[1];
    const float* fstd  = (const float*)d_in[2];
    float* out = (float*)d_out;
    int B = in_sizes[0] / NPIX;

    const size_t msr_bytes = (size_t)FEAT * sizeof(float2);   // 66368
    const size_t map_bytes = (size_t)NHOG * sizeof(int);      // 30048
    if (ws_size >= msr_bytes + map_bytes) {
        float2* msr = (float2*)d_ws;
        int* map = (int*)((char*)d_ws + msr_bytes);
        hipLaunchKernelGGL(setup_kernel, dim3((FEAT + 255) / 256), dim3(256),
                           0, stream, fmean, fstd, msr, map);
        hipLaunchKernelGGL(hog_kernel<true>, dim3(B), dim3(256), 0, stream,
                           x, fmean, fstd, msr, map, out);
    } else {
        hipLaunchKernelGGL(hog_kernel<false>, dim3(B), dim3(256), 0, stream,
                           x, fmean, fstd, nullptr, nullptr, out);
    }
}

// Round 4
// 219.089 us; speedup vs baseline: 3.2910x; 2.2401x over previous
//
#include <hip/hip_runtime.h>
#include <math.h>

// HOG multi-scale feature extractor for 28x28 images. v4:
//  - ATOMIC-FREE histogram build: pixel-parallel (mag,ang) -> LDS, then
//    cell-parallel accumulation in registers (each thread owns one cell,
//    compile-time-unrolled bin select), non-atomic LDS writes. Hist zeroing
//    pass dropped (every bin is written exactly once).
//  - keeps v3's poly-atan orientation, padded hist strides, precomputed
//    epilogue index table + (mean,1/std) in d_ws.

constexpr int NPIX = 784;
constexpr int FEAT = 8296;            // 784 + 1152 + 2304 + 4056
constexpr int PB4 = 9, PB3 = 10, PB2 = 7;   // padded cell strides (bins+1)
constexpr int O4P = 0, O3P = 441, O2P = 1251;
constexpr int HIST_TOT = 2623;        // 441 + 810 + 1372 floats
constexpr int NTASK = 269;            // 36 + 64 + 169 block-norm tasks
constexpr int NHOG = FEAT - NPIX;     // 7512 table entries
constexpr int NCELL = 49 + 81 + 196;  // 326 histogram cells

// ---- output index i in [784,8296) -> packed (task<<12)|hist_idx ----
__device__ __forceinline__ int feat_map(int i) {
    int task, h;
    if (i < 1936) {                    // h4: 36 tasks x 4q x 8 bins
        int k = i - 784;
        int t = k >> 5, r = k & 31;
        int q = r >> 3, j = r & 7;
        int by = t / 6, bx = t - by * 6;
        h = O4P + ((by + (q >> 1)) * 7 + bx + (q & 1)) * PB4 + j;
        task = t;
    } else if (i < 4240) {             // h3: 64 tasks x 4q x 9 bins
        int k = i - 1936;
        int t = k / 36, r = k - t * 36;
        int q = r / 9,  j = r - q * 9;
        int by = t >> 3, bx = t & 7;
        h = O3P + ((by + (q >> 1)) * 9 + bx + (q & 1)) * PB3 + j;
        task = 36 + t;
    } else {                           // h2: 169 tasks x 4q x 6 bins
        int k = i - 4240;
        int t = k / 24, r = k - t * 24;
        int q = r / 6,  j = r - q * 6;
        int by = t / 13, bx = t - by * 13;
        h = O2P + ((by + (q >> 1)) * 14 + bx + (q & 1)) * PB2 + j;
        task = 100 + t;
    }
    return (task << 12) | h;
}

__global__ __launch_bounds__(256)
void setup_kernel(const float* __restrict__ fmean,
                  const float* __restrict__ fstd,
                  float2* __restrict__ msr, int* __restrict__ map) {
    int i = blockIdx.x * 256 + threadIdx.x;
    if (i < FEAT) {
        msr[i] = make_float2(fmean[i], 1.0f / fstd[i]);
        if (i >= NPIX) map[i - NPIX] = feat_map(i);
    }
}

// branchless orientation in degrees == (atan2(gy,gx)*180/pi + 180) mod 180
__device__ __forceinline__ float orient_deg(float gy, float gx) {
    float ax = fabsf(gx), ay = fabsf(gy);
    float mn = fminf(ax, ay), mx = fmaxf(ax, ay);
    float r = __fdividef(mn, mx + 1e-37f);          // [0,1]
    float a = r * r;                                 // A&S 4.4.49, |err|<=1e-5
    float th = ((((0.0208351f * a - 0.0851330f) * a + 0.1801410f) * a
                 - 0.3302995f) * a + 0.9998660f) * r;
    th *= 57.29577951308232f;                        // rad -> deg, [0,45]
    if (ay > ax) th = 90.0f - th;                    // [0,90]
    bool neg = ((__float_as_uint(gx) ^ __float_as_uint(gy)) >> 31) != 0;
    float o = neg ? 180.0f - th : th;
    return (o >= 180.0f) ? 0.0f : o;                 // continuous wrap
}

__device__ __forceinline__ float ldimg(const float* img, int y, int x) {
    return (y >= 0 && y < 28 && x >= 0 && x < 28) ? img[y * 28 + x] : 0.0f;
}

// register-array soft binning; all acc indices compile-time (no scratch)
template <int BINS>
__device__ __forceinline__ void bin_accum(float mag, float ang,
                                          float binw, float inv_binw,
                                          float* acc) {
    int b0 = (int)(ang * inv_binw);                  // ang in [0,180)
    if (b0 > BINS - 1) b0 = BINS - 1;
    float frac = (ang - (float)b0 * binw) * inv_binw;
    float w0 = mag * (1.0f - frac), w1 = mag * frac;
    int b1 = (b0 + 1 == BINS) ? 0 : b0 + 1;
    #pragma unroll
    for (int j = 0; j < BINS; ++j)
        acc[j] += (j == b0) ? w0 : ((j == b1) ? w1 : 0.0f);
}

template <bool USE_TABLE>
__global__ __launch_bounds__(256)
void hog_kernel(const float* __restrict__ x,
                const float* __restrict__ fmean,
                const float* __restrict__ fstd,
                const float2* __restrict__ msr,
                const int* __restrict__ map,
                float* __restrict__ out) {
    __shared__ __align__(16) float img[NPIX];
    __shared__ __align__(16) float2 ma[NPIX];   // (mag, ang) per pixel
    __shared__ float hist[HIST_TOT];
    __shared__ float2 nrm[NTASK];

    const int b = blockIdx.x;
    const int tid = threadIdx.x;
    const float* xb = x + (size_t)b * NPIX;

    // ---- A: load image (coalesced float4) ----
    for (int i = tid; i < NPIX / 4; i += 256)
        reinterpret_cast<float4*>(img)[i] =
            reinterpret_cast<const float4*>(xb)[i];
    __syncthreads();

    // ---- B: pixel-parallel Sobel + (mag, ang) into LDS ----
    for (int p = tid; p < NPIX; p += 256) {
        int y = p / 28, xx = p - (p / 28) * 28;
        float a00 = ldimg(img, y - 1, xx - 1);
        float a01 = ldimg(img, y - 1, xx);
        float a02 = ldimg(img, y - 1, xx + 1);
        float a10 = ldimg(img, y,     xx - 1);
        float a12 = ldimg(img, y,     xx + 1);
        float a20 = ldimg(img, y + 1, xx - 1);
        float a21 = ldimg(img, y + 1, xx);
        float a22 = ldimg(img, y + 1, xx + 1);
        float gxv = (a00 + 2.0f * a10 + a20 - a02 - 2.0f * a12 - a22) * 0.25f;
        float gyv = (a00 + 2.0f * a01 + a02 - a20 - 2.0f * a21 - a22) * 0.25f;
        float mag = sqrtf(gxv * gxv + gyv * gyv + 1e-6f);
        ma[p] = make_float2(mag, orient_deg(gyv, gxv));
    }
    __syncthreads();

    // ---- C: cell-parallel atomic-free histogram accumulation ----
    for (int t = tid; t < NCELL; t += 256) {
        if (t < 49) {                      // cell=4, bins=8, 16 px
            int cy = t / 7, cx = t - cy * 7;
            int p0 = (cy * 28 + cx) * 4;
            float acc[8] = {};
            #pragma unroll
            for (int py = 0; py < 4; ++py)
                #pragma unroll
                for (int px = 0; px < 4; ++px) {
                    float2 m = ma[p0 + py * 28 + px];
                    bin_accum<8>(m.x, m.y, 22.5f, 1.0f / 22.5f, acc);
                }
            #pragma unroll
            for (int j = 0; j < 8; ++j) hist[O4P + t * PB4 + j] = acc[j];
        } else if (t < 130) {              // cell=3, bins=9, 9-16 px
            int k = t - 49;
            int cy = k / 9, cx = k - cy * 9;
            int y0 = cy * 3, y1 = (cy == 8) ? 28 : y0 + 3;
            int x0 = cx * 3, x1 = (cx == 8) ? 28 : x0 + 3;
            float acc[9] = {};
            for (int y = y0; y < y1; ++y)
                for (int xx = x0; xx < x1; ++xx) {
                    float2 m = ma[y * 28 + xx];
                    bin_accum<9>(m.x, m.y, 20.0f, 0.05f, acc);
                }
            #pragma unroll
            for (int j = 0; j < 9; ++j) hist[O3P + k * PB3 + j] = acc[j];
        } else {                           // cell=2, bins=6, 4 px
            int k = t - 130;
            int cy = k / 14, cx = k - cy * 14;
            int p0 = (cy * 28 + cx) * 2;
            float acc[6] = {};
            #pragma unroll
            for (int py = 0; py < 2; ++py)
                #pragma unroll
                for (int px = 0; px < 2; ++px) {
                    float2 m = ma[p0 + py * 28 + px];
                    bin_accum<6>(m.x, m.y, 30.0f, 1.0f / 30.0f, acc);
                }
            #pragma unroll
            for (int j = 0; j < 6; ++j) hist[O2P + k * PB2 + j] = acc[j];
        }
    }
    __syncthreads();

    // ---- D: per-task L2-hys norm factors ----
    for (int t = tid; t < NTASK; t += 256) {
        int bins, Wc, pb, hoff, by, bx;
        if (t < 36)       { bins = 8; pb = PB4; Wc = 7;  hoff = O4P;
                            by = t / 6; bx = t - by * 6; }
        else if (t < 100) { int k = t - 36; bins = 9; pb = PB3; Wc = 9; hoff = O3P;
                            by = k >> 3; bx = k & 7; }
        else              { int k = t - 100; bins = 6; pb = PB2; Wc = 14; hoff = O2P;
                            by = k / 13; bx = k - by * 13; }
        int c00 = hoff + (by * Wc + bx) * pb;
        int cb[4] = {c00, c00 + pb, c00 + Wc * pb, c00 + (Wc + 1) * pb};

        float s = 0.0f;
        #pragma unroll
        for (int q = 0; q < 4; ++q)
            for (int j = 0; j < bins; ++j) {
                float v = hist[cb[q] + j];
                s += v * v;
            }
        float ninv = 1.0f / sqrtf(s + 1e-6f);

        float s2 = 0.0f;
        #pragma unroll
        for (int q = 0; q < 4; ++q)
            for (int j = 0; j < bins; ++j) {
                float c = fminf(hist[cb[q] + j] * ninv, 0.2f);
                s2 += c * c;
            }
        nrm[t] = make_float2(ninv, 1.0f / sqrtf(s2 + 1e-6f));
    }
    __syncthreads();

    // ---- E: epilogue, coalesced float4 writes ----
    float4* outp = reinterpret_cast<float4*>(out + (size_t)b * FEAT);

    for (int i4 = tid; i4 < NPIX / 4; i4 += 256) {
        float4 v = reinterpret_cast<const float4*>(img)[i4];
        float4 r;
        if (USE_TABLE) {
            const float4* msr4 = reinterpret_cast<const float4*>(msr);
            float4 p0 = msr4[i4 * 2], p1 = msr4[i4 * 2 + 1];
            r.x = (v.x - p0.x) * p0.y;  r.y = (v.y - p0.z) * p0.w;
            r.z = (v.z - p1.x) * p1.y;  r.w = (v.w - p1.z) * p1.w;
        } else {
            int i = i4 * 4;
            r.x = (v.x - fmean[i])     / fstd[i];
            r.y = (v.y - fmean[i + 1]) / fstd[i + 1];
            r.z = (v.z - fmean[i + 2]) / fstd[i + 2];
            r.w = (v.w - fmean[i + 3]) / fstd[i + 3];
        }
        outp[i4] = r;
    }

    for (int t4 = tid; t4 < NHOG / 4; t4 += 256) {
        int i4 = NPIX / 4 + t4;
        int mp[4];
        if (USE_TABLE) {
            int4 m4 = reinterpret_cast<const int4*>(map)[t4];
            mp[0] = m4.x; mp[1] = m4.y; mp[2] = m4.z; mp[3] = m4.w;
        } else {
            #pragma unroll
            for (int e = 0; e < 4; ++e) mp[e] = feat_map(i4 * 4 + e);
        }
        float vv[4];
        #pragma unroll
        for (int e = 0; e < 4; ++e) {
            int task = mp[e] >> 12, h = mp[e] & 4095;
            float2 n = nrm[task];
            vv[e] = fminf(hist[h] * n.x, 0.2f) * n.y;
        }
        float4 r;
        if (USE_TABLE) {
            const float4* msr4 = reinterpret_cast<const float4*>(msr);
            float4 p0 = msr4[i4 * 2], p1 = msr4[i4 * 2 + 1];
            r.x = (vv[0] - p0.x) * p0.y;  r.y = (vv[1] - p0.z) * p0.w;
            r.z = (vv[2] - p1.x) * p1.y;  r.w = (vv[3] - p1.z) * p1.w;
        } else {
            int i = i4 * 4;
            r.x = (vv[0] - fmean[i])     / fstd[i];
            r.y = (vv[1] - fmean[i + 1]) / fstd[i + 1];
            r.z = (vv[2] - fmean[i + 2]) / fstd[i + 2];
            r.w = (vv[3] - fmean[i + 3]) / fstd[i + 3];
        }
        outp[i4] = r;
    }
}

extern "C" void kernel_launch(void* const* d_in, const int* in_sizes, int n_in,
                              void* d_out, int out_size, void* d_ws, size_t ws_size,
                              hipStream_t stream) {
    const float* x     = (const float*)d_in[0];
    const float* fmean = (const float*)d_in[1];
    const float* fstd  = (const float*)d_in[2];
    float* out = (float*)d_out;
    int B = in_sizes[0] / NPIX;

    const size_t msr_bytes = (size_t)FEAT * sizeof(float2);   // 66368
    const size_t map_bytes = (size_t)NHOG * sizeof(int);      // 30048
    if (ws_size >= msr_bytes + map_bytes) {
        float2* msr = (float2*)d_ws;
        int* map = (int*)((char*)d_ws + msr_bytes);
        hipLaunchKernelGGL(setup_kernel, dim3((FEAT + 255) / 256), dim3(256),
                           0, stream, fmean, fstd, msr, map);
        hipLaunchKernelGGL(hog_kernel<true>, dim3(B), dim3(256), 0, stream,
                           x, fmean, fstd, msr, map, out);
    } else {
        hipLaunchKernelGGL(hog_kernel<false>, dim3(B), dim3(256), 0, stream,
                           x, fmean, fstd, nullptr, nullptr, out);
    }
}

// Round 6
// 205.525 us; speedup vs baseline: 3.5081x; 1.0660x over previous
//
#include <hip/hip_runtime.h>
#include <math.h>

// HOG multi-scale feature extractor for 28x28 images. v6 (= v5 + bugfix):
//  - phase C: unified scale-agnostic per-cell accumulation, exclusive LDS
//    RMW (no atomics). FIX vs v5: each owner zeros its own bin slots first
//    (v5 accumulated into uninitialized LDS), and b0 is clamped to bins-1.
//  - keeps pixel-parallel (mag,ang) precompute, padded hist strides,
//    precomputed epilogue index table + (mean,1/std) in d_ws.

constexpr int NPIX = 784;
constexpr int FEAT = 8296;            // 784 + 1152 + 2304 + 4056
constexpr int PB4 = 9, PB3 = 10, PB2 = 7;   // padded cell strides (bins+1)
constexpr int O4P = 0, O3P = 441, O2P = 1251;
constexpr int HIST_TOT = 2623;        // 441 + 810 + 1372 floats
constexpr int NTASK = 269;            // 36 + 64 + 169 block-norm tasks
constexpr int NHOG = FEAT - NPIX;     // 7512 table entries
constexpr int NCELL = 49 + 81 + 196;  // 326 histogram cells

// ---- output index i in [784,8296) -> packed (task<<12)|hist_idx ----
__device__ __forceinline__ int feat_map(int i) {
    int task, h;
    if (i < 1936) {                    // h4: 36 tasks x 4q x 8 bins
        int k = i - 784;
        int t = k >> 5, r = k & 31;
        int q = r >> 3, j = r & 7;
        int by = t / 6, bx = t - by * 6;
        h = O4P + ((by + (q >> 1)) * 7 + bx + (q & 1)) * PB4 + j;
        task = t;
    } else if (i < 4240) {             // h3: 64 tasks x 4q x 9 bins
        int k = i - 1936;
        int t = k / 36, r = k - t * 36;
        int q = r / 9,  j = r - q * 9;
        int by = t >> 3, bx = t & 7;
        h = O3P + ((by + (q >> 1)) * 9 + bx + (q & 1)) * PB3 + j;
        task = 36 + t;
    } else {                           // h2: 169 tasks x 4q x 6 bins
        int k = i - 4240;
        int t = k / 24, r = k - t * 24;
        int q = r / 6,  j = r - q * 6;
        int by = t / 13, bx = t - by * 13;
        h = O2P + ((by + (q >> 1)) * 14 + bx + (q & 1)) * PB2 + j;
        task = 100 + t;
    }
    return (task << 12) | h;
}

__global__ __launch_bounds__(256)
void setup_kernel(const float* __restrict__ fmean,
                  const float* __restrict__ fstd,
                  float2* __restrict__ msr, int* __restrict__ map) {
    int i = blockIdx.x * 256 + threadIdx.x;
    if (i < FEAT) {
        msr[i] = make_float2(fmean[i], 1.0f / fstd[i]);
        if (i >= NPIX) map[i - NPIX] = feat_map(i);
    }
}

// branchless orientation in degrees == (atan2(gy,gx)*180/pi + 180) mod 180
__device__ __forceinline__ float orient_deg(float gy, float gx) {
    float ax = fabsf(gx), ay = fabsf(gy);
    float mn = fminf(ax, ay), mx = fmaxf(ax, ay);
    float r = __fdividef(mn, mx + 1e-37f);          // [0,1]
    float a = r * r;                                 // A&S 4.4.49, |err|<=1e-5
    float th = ((((0.0208351f * a - 0.0851330f) * a + 0.1801410f) * a
                 - 0.3302995f) * a + 0.9998660f) * r;
    th *= 57.29577951308232f;                        // rad -> deg, [0,45]
    if (ay > ax) th = 90.0f - th;                    // [0,90]
    bool neg = ((__float_as_uint(gx) ^ __float_as_uint(gy)) >> 31) != 0;
    float o = neg ? 180.0f - th : th;
    return (o >= 180.0f) ? 0.0f : o;                 // continuous wrap
}

__device__ __forceinline__ float ldimg(const float* img, int y, int x) {
    return (y >= 0 && y < 28 && x >= 0 && x < 28) ? img[y * 28 + x] : 0.0f;
}

template <bool USE_TABLE>
__global__ __launch_bounds__(256)
void hog_kernel(const float* __restrict__ x,
                const float* __restrict__ fmean,
                const float* __restrict__ fstd,
                const float2* __restrict__ msr,
                const int* __restrict__ map,
                float* __restrict__ out) {
    __shared__ __align__(16) float img[NPIX];
    __shared__ __align__(16) float2 ma[NPIX];   // (mag, ang) per pixel
    __shared__ float hist[HIST_TOT];
    __shared__ float2 nrm[NTASK];

    const int b = blockIdx.x;
    const int tid = threadIdx.x;
    const float* xb = x + (size_t)b * NPIX;

    // ---- A: load image (coalesced float4) ----
    for (int i = tid; i < NPIX / 4; i += 256)
        reinterpret_cast<float4*>(img)[i] =
            reinterpret_cast<const float4*>(xb)[i];
    __syncthreads();

    // ---- B: pixel-parallel Sobel + (mag, ang) into LDS ----
    for (int p = tid; p < NPIX; p += 256) {
        int y = p / 28, xx = p - (p / 28) * 28;
        float a00 = ldimg(img, y - 1, xx - 1);
        float a01 = ldimg(img, y - 1, xx);
        float a02 = ldimg(img, y - 1, xx + 1);
        float a10 = ldimg(img, y,     xx - 1);
        float a12 = ldimg(img, y,     xx + 1);
        float a20 = ldimg(img, y + 1, xx - 1);
        float a21 = ldimg(img, y + 1, xx);
        float a22 = ldimg(img, y + 1, xx + 1);
        float gxv = (a00 + 2.0f * a10 + a20 - a02 - 2.0f * a12 - a22) * 0.25f;
        float gyv = (a00 + 2.0f * a01 + a02 - a20 - 2.0f * a21 - a22) * 0.25f;
        float mag = sqrtf(gxv * gxv + gyv * gyv + 1e-6f);
        ma[p] = make_float2(mag, orient_deg(gyv, gxv));
    }
    __syncthreads();

    // ---- C: unified cell-parallel accumulation (exclusive LDS RMW) ----
    for (int t = tid; t < NCELL; t += 256) {
        int base, y0, x0, ny, nx, bins;
        float invbw;                       // bins / 180
        if (t < 49) {                      // cell=4, bins=8, 4x4 px
            int cy = t / 7, cx = t - cy * 7;
            y0 = cy * 4; x0 = cx * 4; ny = 4; nx = 4;
            bins = 8; invbw = 8.0f / 180.0f;
            base = O4P + t * PB4;
        } else if (t < 130) {              // cell=3, bins=9, 3-4 x 3-4 px
            int k = t - 49;
            int cy = k / 9, cx = k - cy * 9;
            y0 = cy * 3; x0 = cx * 3;
            ny = (cy == 8) ? 4 : 3; nx = (cx == 8) ? 4 : 3;
            bins = 9; invbw = 9.0f / 180.0f;
            base = O3P + k * PB3;
        } else {                           // cell=2, bins=6, 2x2 px
            int k = t - 130;
            int cy = k / 14, cx = k - cy * 14;
            y0 = cy * 2; x0 = cx * 2; ny = 2; nx = 2;
            bins = 6; invbw = 6.0f / 180.0f;
            base = O2P + k * PB2;
        }
        // exclusive owner: zero own bins first (v5 bug: missing)
        for (int j = 0; j < bins; ++j) hist[base + j] = 0.0f;
        for (int iy = 0; iy < ny; ++iy) {
            int row = (y0 + iy) * 28 + x0;
            for (int ix = 0; ix < nx; ++ix) {
                float2 m = ma[row + ix];
                float tb = m.y * invbw;            // in [0, bins)
                int b0 = (int)tb;
                if (b0 > bins - 1) b0 = bins - 1;  // float-edge guard
                float frac = tb - (float)b0;
                float w1 = m.x * frac;
                float w0 = m.x - w1;
                int b1 = b0 + 1; if (b1 == bins) b1 = 0;
                hist[base + b0] += w0;             // exclusive owner: no atomic
                hist[base + b1] += w1;
            }
        }
    }
    __syncthreads();

    // ---- D: per-task L2-hys norm factors ----
    for (int t = tid; t < NTASK; t += 256) {
        int bins, Wc, pb, hoff, by, bx;
        if (t < 36)       { bins = 8; pb = PB4; Wc = 7;  hoff = O4P;
                            by = t / 6; bx = t - by * 6; }
        else if (t < 100) { int k = t - 36; bins = 9; pb = PB3; Wc = 9; hoff = O3P;
                            by = k >> 3; bx = k & 7; }
        else              { int k = t - 100; bins = 6; pb = PB2; Wc = 14; hoff = O2P;
                            by = k / 13; bx = k - by * 13; }
        int c00 = hoff + (by * Wc + bx) * pb;
        int cb[4] = {c00, c00 + pb, c00 + Wc * pb, c00 + (Wc + 1) * pb};

        float s = 0.0f;
        #pragma unroll
        for (int q = 0; q < 4; ++q)
            for (int j = 0; j < bins; ++j) {
                float v = hist[cb[q] + j];
                s += v * v;
            }
        float ninv = 1.0f / sqrtf(s + 1e-6f);

        float s2 = 0.0f;
        #pragma unroll
        for (int q = 0; q < 4; ++q)
            for (int j = 0; j < bins; ++j) {
                float c = fminf(hist[cb[q] + j] * ninv, 0.2f);
                s2 += c * c;
            }
        nrm[t] = make_float2(ninv, 1.0f / sqrtf(s2 + 1e-6f));
    }
    __syncthreads();

    // ---- E: epilogue, coalesced float4 writes ----
    float4* outp = reinterpret_cast<float4*>(out + (size_t)b * FEAT);

    for (int i4 = tid; i4 < NPIX / 4; i4 += 256) {
        float4 v = reinterpret_cast<const float4*>(img)[i4];
        float4 r;
        if (USE_TABLE) {
            const float4* msr4 = reinterpret_cast<const float4*>(msr);
            float4 p0 = msr4[i4 * 2], p1 = msr4[i4 * 2 + 1];
            r.x = (v.x - p0.x) * p0.y;  r.y = (v.y - p0.z) * p0.w;
            r.z = (v.z - p1.x) * p1.y;  r.w = (v.w - p1.z) * p1.w;
        } else {
            int i = i4 * 4;
            r.x = (v.x - fmean[i])     / fstd[i];
            r.y = (v.y - fmean[i + 1]) / fstd[i + 1];
            r.z = (v.z - fmean[i + 2]) / fstd[i + 2];
            r.w = (v.w - fmean[i + 3]) / fstd[i + 3];
        }
        outp[i4] = r;
    }

    for (int t4 = tid; t4 < NHOG / 4; t4 += 256) {
        int i4 = NPIX / 4 + t4;
        int mp[4];
        if (USE_TABLE) {
            int4 m4 = reinterpret_cast<const int4*>(map)[t4];
            mp[0] = m4.x; mp[1] = m4.y; mp[2] = m4.z; mp[3] = m4.w;
        } else {
            #pragma unroll
            for (int e = 0; e < 4; ++e) mp[e] = feat_map(i4 * 4 + e);
        }
        float vv[4];
        #pragma unroll
        for (int e = 0; e < 4; ++e) {
            int task = mp[e] >> 12, h = mp[e] & 4095;
            float2 n = nrm[task];
            vv[e] = fminf(hist[h] * n.x, 0.2f) * n.y;
        }
        float4 r;
        if (USE_TABLE) {
            const float4* msr4 = reinterpret_cast<const float4*>(msr);
            float4 p0 = msr4[i4 * 2], p1 = msr4[i4 * 2 + 1];
            r.x = (vv[0] - p0.x) * p0.y;  r.y = (vv[1] - p0.z) * p0.w;
            r.z = (vv[2] - p1.x) * p1.y;  r.w = (vv[3] - p1.z) * p1.w;
        } else {
            int i = i4 * 4;
            r.x = (vv[0] - fmean[i])     / fstd[i];
            r.y = (vv[1] - fmean[i + 1]) / fstd[i + 1];
            r.z = (vv[2] - fmean[i + 2]) / fstd[i + 2];
            r.w = (vv[3] - fmean[i + 3]) / fstd[i + 3];
        }
        outp[i4] = r;
    }
}

extern "C" void kernel_launch(void* const* d_in, const int* in_sizes, int n_in,
                              void* d_out, int out_size, void* d_ws, size_t ws_size,
                              hipStream_t stream) {
    const float* x     = (const float*)d_in[0];
    const float* fmean = (const float*)d_in[1];
    const float* fstd  = (const float*)d_in[2];
    float* out = (float*)d_out;
    int B = in_sizes[0] / NPIX;

    const size_t msr_bytes = (size_t)FEAT * sizeof(float2);   // 66368
    const size_t map_bytes = (size_t)NHOG * sizeof(int);      // 30048
    if (ws_size >= msr_bytes + map_bytes) {
        float2* msr = (float2*)d_ws;
        int* map = (int*)((char*)d_ws + msr_bytes);
        hipLaunchKernelGGL(setup_kernel, dim3((FEAT + 255) / 256), dim3(256),
                           0, stream, fmean, fstd, msr, map);
        hipLaunchKernelGGL(hog_kernel<true>, dim3(B), dim3(256), 0, stream,
                           x, fmean, fstd, msr, map, out);
    } else {
        hipLaunchKernelGGL(hog_kernel<false>, dim3(B), dim3(256), 0, stream,
                           x, fmean, fstd, nullptr, nullptr, out);
    }
}